// Round 4
// baseline (38877.243 us; speedup 1.0000x reference)
//
#include <hip/hip_runtime.h>

// Seq2Seq LSTM (2-layer enc 512 steps + 2-layer dec 96 steps), B=512, H=512.
// R8 = R7 (LDS-staged A-operand via global_load_lds, 512 thr / 8 waves,
//      kh K-half split, global lockstep barrier) + L2-conflict fix:
//  - WEIGHTS REPACKED per hj_tile: row order hj*128 + gate*32 + lj, each row
//    [K hi][K lo] (pitch 2K). Old layout's gate-major rows put one XCD's
//    ~1.7 MB slice in 64 KB blocks at 1 MB strides -> all alias the same L2
//    sets (way-size 256 KB, 1 MB % 256 KB = 0), needing ~26 ways of 16 ->
//    conflict thrash -> full weight restream every phase (FETCH 13 MB/phase,
//    observed R4-R7). Packed slices are contiguous -> uniformly spread over
//    sets -> resident across phases.
//  - staged h DMA aux 0x11 -> 0x13 (adds NT): no L2 allocation even if the
//    agent-scope read passes through TCC.
// Everything else identical to R7.

typedef unsigned int u32;
typedef unsigned short u16;

using bf16x8  = __attribute__((ext_vector_type(8))) __bf16;
using u16x8   = __attribute__((ext_vector_type(8))) u16;
using floatx4 = __attribute__((ext_vector_type(4))) float;

#define NWG 256
#define HB  262144   // 512*512 elements of one h/c plane

// packed region sizes (elements) per hj_tile: 128 rows x 2*K
#define ENC0_REG (128 * 2 * 640)
#define ENC1_REG (128 * 2 * 1024)
#define DEC0_REG (128 * 2 * 512)
#define DEC1_REG (128 * 2 * 1024)

// LDS map (dynamic, 131072 B):
//   [0..65536)      A-region H0: hi chunks ([k8][row]), lo at +32768 B
//   [65536..131072) A-region H1: same layout
//   xb reduce buffer (32 KB) aliases [0..32768) after GEMMs complete.
#define H0_CHUNK 0
#define H1_CHUNK 4096
#define LO_BYTES 32768

#define AS1C(p) ((const __attribute__((address_space(1))) void*)(p))
#define AS3(p)  ((__attribute__((address_space(3))) void*)(u32)(size_t)(p))

__device__ __forceinline__ u16 f2bf(float f) {
  u32 u = __builtin_bit_cast(u32, f);
  u += 0x7FFFu + ((u >> 16) & 1u);   // RNE
  return (u16)(u >> 16);
}
__device__ __forceinline__ float bf2f(u16 h) {
  return __builtin_bit_cast(float, (u32)h << 16);
}
__device__ __forceinline__ bf16x8 ld8(const u16* p) {           // cached (L1/L2)
  return __builtin_bit_cast(bf16x8, *reinterpret_cast<const u16x8*>(p));
}
__device__ __forceinline__ float sig_(float x) {
  x = fminf(fmaxf(x, -30.f), 30.f);
  return 1.f / (1.f + __expf(-x));
}
__device__ __forceinline__ float tanh_(float x) {
  x = fminf(fmaxf(x, -15.f), 15.f);
  float e = __expf(2.f * x);
  return (e - 1.f) / (e + 1.f);
}

#define MFMA(a, b, c) __builtin_amdgcn_mfma_f32_16x16x32_bf16((a), (b), (c), 0, 0, 0)

// ---- GEMM segment, A from LDS ([k8][row] chunks), W packed-region loads ----
// Wreg = region base (+K-offset for cat parts). Row (g*32+lj), pitch 2*S,
// lo plane at +S within the row.
__device__ __forceinline__ void gemm_lds(floatx4* acc, const char* apb,
    const u16* __restrict__ Wreg, int strideW,
    int lj0, int l15, int quad, int kbeg, int kend)
{
  const u16* wp = Wreg + (size_t)(lj0 + l15) * 2 * strideW + (quad << 3);
  const size_t gs = (size_t)strideW << 6;   // 32 rows * 2 * strideW
  #pragma unroll 2
  for (int k = kbeg; k < kend; k += 32) {
    const int kb8 = ((k >> 3) + quad) << 9;          // k8 * 512 bytes
    bf16x8 ah = *reinterpret_cast<const bf16x8*>(apb + kb8);
    bf16x8 al = *reinterpret_cast<const bf16x8*>(apb + kb8 + LO_BYTES);
    #pragma unroll
    for (int g = 0; g < 4; ++g) {
      bf16x8 wh = ld8(wp + k + g * gs);
      bf16x8 wl = ld8(wp + k + g * gs + strideW);
      acc[g] = MFMA(ah, wh, acc[g]);
      acc[g] = MFMA(ah, wl, acc[g]);
      acc[g] = MFMA(al, wh, acc[g]);
    }
  }
}

// ---- K=128 segment reading X_encode fp32 (B,T,128), split on the fly -------
__device__ __forceinline__ void gemm_x128s(floatx4* acc,
    const float* __restrict__ X, int t,
    const u16* __restrict__ Wreg, int strideW,
    int row0, int lj0, int lane)
{
  const int quad = lane >> 4, l15 = lane & 15;
  const float* xp = X + ((size_t)(row0 + l15) * 512 + t) * 128 + (quad << 3);
  const u16* wp = Wreg + (size_t)(lj0 + l15) * 2 * strideW + (quad << 3);
  const size_t gs = (size_t)strideW << 6;
  #pragma unroll
  for (int k = 0; k < 128; k += 32) {
    floatx4 xa = *reinterpret_cast<const floatx4*>(xp + k);
    floatx4 xb_ = *reinterpret_cast<const floatx4*>(xp + k + 4);
    u16x8 uh, ul;
    #pragma unroll
    for (int i = 0; i < 4; ++i) {
      u16 h0 = f2bf(xa[i]);  uh[i] = h0;     ul[i] = f2bf(xa[i] - bf2f(h0));
      u16 h1 = f2bf(xb_[i]); uh[4 + i] = h1; ul[4 + i] = f2bf(xb_[i] - bf2f(h1));
    }
    bf16x8 ah = __builtin_bit_cast(bf16x8, uh);
    bf16x8 al = __builtin_bit_cast(bf16x8, ul);
    #pragma unroll
    for (int g = 0; g < 4; ++g) {
      bf16x8 wh = ld8(wp + k + g * gs);
      bf16x8 wl = ld8(wp + k + g * gs + strideW);
      acc[g] = MFMA(ah, wh, acc[g]);
      acc[g] = MFMA(ah, wl, acc[g]);
      acc[g] = MFMA(al, wh, acc[g]);
    }
  }
}

__device__ __forceinline__ void store_h_split(u16* __restrict__ hout,
                                              size_t off, float h) {
  u16 hh = f2bf(h);
  u16 hl = f2bf(h - bf2f(hh));
  __hip_atomic_store(hout + off,      hh, __ATOMIC_RELAXED, __HIP_MEMORY_SCOPE_AGENT);
  __hip_atomic_store(hout + off + HB, hl, __ATOMIC_RELAXED, __HIP_MEMORY_SCOPE_AGENT);
}

// ---- LSTM cell epilogues (C/D layout: col=lane&15, row=(lane>>4)*4+reg) ----
__device__ __forceinline__ void cell_store(const floatx4* acc,
    float* __restrict__ c, u16* __restrict__ hout,
    const float* __restrict__ bs, int row0, int j0, int lane)
{
  const int quad = lane >> 4, l15 = lane & 15;
  const int col = j0 + l15;
  const float bi = bs[col], bff = bs[512 + col], bg = bs[1024 + col], bo = bs[1536 + col];
  const int r0 = row0 + (quad << 2);
  #pragma unroll
  for (int r = 0; r < 4; ++r) {
    const size_t off = ((size_t)(r0 + r) << 9) + col;
    float ii = sig_(acc[0][r] + bi);
    float ff = sig_(acc[1][r] + bff);
    float gg = tanh_(acc[2][r] + bg);
    float oo = sig_(acc[3][r] + bo);
    float cn = ff * c[off] + ii * gg;
    c[off] = cn;
    store_h_split(hout, off, oo * tanh_(cn));
  }
}

// decoder layer0: adds rank-1 input term inp[b]*W_ih0[j] (fp32, exact)
__device__ __forceinline__ void cell_store_dec0(const floatx4* acc,
    float* __restrict__ c, u16* __restrict__ hout,
    const float* __restrict__ bs, const float* __restrict__ w0col,
    const float* __restrict__ din0, const float* __restrict__ y,
    const int* __restrict__ tfm, float* __restrict__ dout,
    int t, int row0, int j0, int lane)
{
  const int quad = lane >> 4, l15 = lane & 15;
  const int col = j0 + l15;
  const float bi = bs[col], bff = bs[512 + col], bg = bs[1024 + col], bo = bs[1536 + col];
  const float wi = w0col[col], wf = w0col[512 + col], wg = w0col[1024 + col], wo = w0col[1536 + col];
  const int r0 = row0 + (quad << 2);
  #pragma unroll
  for (int r = 0; r < 4; ++r) {
    const int row = r0 + r;
    float inp;
    if (t == 0) inp = din0[row];
    else if (tfm[t - 1] != 0) inp = y[row * 96 + t];
    else inp = __hip_atomic_load(dout + row * 96 + (t - 1),
                                 __ATOMIC_RELAXED, __HIP_MEMORY_SCOPE_AGENT);
    const size_t off = ((size_t)row << 9) + col;
    float ii = sig_(acc[0][r] + bi + inp * wi);
    float ff = sig_(acc[1][r] + bff + inp * wf);
    float gg = tanh_(acc[2][r] + bg + inp * wg);
    float oo = sig_(acc[3][r] + bo + inp * wo);
    float cn = ff * c[off] + ii * gg;
    c[off] = cn;
    store_h_split(hout, off, oo * tanh_(cn));
  }
}

// decoder layer1: cell + fc partial dot (shuffle-reduce 16 cols, atomicAdd)
__device__ __forceinline__ void cell_store_dec1(const floatx4* acc,
    float* __restrict__ c, u16* __restrict__ hout,
    const float* __restrict__ bs, const float* __restrict__ fcW,
    const float* __restrict__ fcb, float* __restrict__ dout,
    int t, int row0, int j0, int lane)
{
  const int quad = lane >> 4, l15 = lane & 15;
  const int col = j0 + l15;
  const float bi = bs[col], bff = bs[512 + col], bg = bs[1024 + col], bo = bs[1536 + col];
  const float fw = fcW[col];
  const int r0 = row0 + (quad << 2);
  float s[4];
  #pragma unroll
  for (int r = 0; r < 4; ++r) {
    const size_t off = ((size_t)(r0 + r) << 9) + col;
    float ii = sig_(acc[0][r] + bi);
    float ff = sig_(acc[1][r] + bff);
    float gg = tanh_(acc[2][r] + bg);
    float oo = sig_(acc[3][r] + bo);
    float cn = ff * c[off] + ii * gg;
    c[off] = cn;
    float h = oo * tanh_(cn);
    store_h_split(hout, off, h);
    s[r] = h * fw;
  }
  #pragma unroll
  for (int m = 1; m < 16; m <<= 1) {
    #pragma unroll
    for (int r = 0; r < 4; ++r) s[r] += __shfl_xor(s[r], m, 64);
  }
  if (l15 == 0) {
    #pragma unroll
    for (int r = 0; r < 4; ++r) {
      float v = s[r];
      if (j0 == 0) v += fcb[0];            // exactly one wave per (b,t) adds bias
      atomicAdd(&dout[(size_t)(r0 + r) * 96 + t], v);
    }
  }
}

// ---- persistent kernel -----------------------------------------------------
__global__ __launch_bounds__(512) void seq2seq_persist(
    const float* __restrict__ Xenc, const float* __restrict__ y,
    const int* __restrict__ tfm, const float* __restrict__ dWih0col,
    const float* __restrict__ fcW, const float* __restrict__ fcb,
    const u16* __restrict__ enc0, const u16* __restrict__ enc1,
    const u16* __restrict__ dec0w, const u16* __restrict__ dec1,
    u16* __restrict__ h0bufs, u16* __restrict__ h1bufs,
    float* __restrict__ c0, float* __restrict__ c1,
    const float* __restrict__ bsum, const float* __restrict__ din0,
    float* __restrict__ dout, u32* __restrict__ bar)
{
  extern __shared__ char smem_c[];
  const int tid = threadIdx.x;
  const int g = blockIdx.x;
  const int wave = tid >> 6, lane = tid & 63;
  const int w4 = wave & 3, kh = wave >> 2;      // tile-quadrant, K-half
  const int quad = lane >> 4, l15 = lane & 15;
  // XCD-aware swizzle: WGs sharing a W-slab (same hj_tile) land on one XCD
  const int q = g >> 3;
  const int hj_tile = (g & 7) + ((q & 1) << 3);  // 0..15
  const int b_tile = q >> 1;                     // 0..15
  const int b0 = b_tile << 5, hj0 = hj_tile << 5;
  const int row0 = b0 + ((w4 & 1) << 4);         // 16 batch rows
  const int j0 = hj0 + ((w4 >> 1) << 4);         // 16 h-cols (global)
  const int lj0 = (w4 >> 1) << 4;                // local col within hj region
  const int slot = g & 7;
  u16* h0buf[2] = { h0bufs, h0bufs + 2 * HB };
  u16* h1buf[2] = { h1bufs, h1bufs + 2 * HB };
  unsigned ep = 0;

  // packed weight region bases for this hj_tile
  const u16* enc0r = enc0  + (size_t)hj_tile * ENC0_REG;
  const u16* enc1r = enc1  + (size_t)hj_tile * ENC1_REG;
  const u16* dec0r = dec0w + (size_t)hj_tile * DEC0_REG;
  const u16* dec1r = dec1  + (size_t)hj_tile * DEC1_REG;

  // A-fragment base pointers (row within WG = (w4&1)*16 + l15)
  const int lrow = ((w4 & 1) << 4) + l15;
  const char* apb0 = smem_c + lrow * 16;           // H0 region
  const char* apb1 = smem_c + 65536 + lrow * 16;   // H1 region
  floatx4* xb = (floatx4*)smem_c;                  // 32 KB alias (dead-A reuse)
  #define XR(w4_, L_, g_) (((((w4_) * 2 + (L_)) * 4 + (g_)) << 6) + lane)

  // stage one h buffer (hi plane + lo at +HB) into an A-region.
  // chunk c in [0,4096): half=c>>11 (hi/lo), k8=(c&2047)>>5, row=c&31.
  // aux 0x13 = SC0|NT|SC1: LLC-coherent, L2 no-allocate.
  auto stage = [&](const u16* hbuf, int region_chunk) {
    #pragma unroll
    for (int blk = 0; blk < 8; ++blk) {
      const int cw = (blk << 9) + (wave << 6);        // wave-uniform chunk base
      const int c  = cw + lane;
      const int half = c >> 11, cc = c & 2047;
      const int k8 = cc >> 5, row = cc & 31;
      const u16* src = hbuf + (size_t)half * HB
                     + ((size_t)(b0 + row) << 9) + (k8 << 3);
      __builtin_amdgcn_global_load_lds(
          AS1C(src), AS3(smem_c + (size_t)(region_chunk + cw) * 16),
          16, 0, 0x13 /* SC0|NT|SC1 */);
    }
  };

  // GLOBAL two-level lockstep barrier: monotonic relaxed counters.
  auto gbar = [&]() {
    __syncthreads();
    ++ep;
    if (tid == 0) {
      u32 prev = __hip_atomic_fetch_add(&bar[slot * 32], 1u,
                     __ATOMIC_RELAXED, __HIP_MEMORY_SCOPE_AGENT);
      if (prev == ep * 32u - 1u) {
        u32 pm = __hip_atomic_fetch_add(&bar[256], 1u,
                     __ATOMIC_RELAXED, __HIP_MEMORY_SCOPE_AGENT);
        if (pm == ep * 8u - 1u)
          __hip_atomic_store(&bar[288], ep,
                     __ATOMIC_RELAXED, __HIP_MEMORY_SCOPE_AGENT);
      }
      while (__hip_atomic_load(&bar[288],
                 __ATOMIC_RELAXED, __HIP_MEMORY_SCOPE_AGENT) < ep)
        __builtin_amdgcn_s_sleep(1);
    }
    asm volatile("" ::: "memory");
    __syncthreads();
  };

  // ---------------- encoder: phase p does layer1[p-1] and layer0[p] ----------
  for (int p = 0; p <= 512; ++p) {
    const int cur = p & 1, nxt = cur ^ 1;
    stage(h0buf[cur], H0_CHUNK);
    stage(h1buf[cur], H1_CHUNK);
    __syncthreads();                       // drains staging vmcnt
    floatx4 a1[4] = { floatx4{0,0,0,0}, floatx4{0,0,0,0}, floatx4{0,0,0,0}, floatx4{0,0,0,0} };
    floatx4 a0[4] = { floatx4{0,0,0,0}, floatx4{0,0,0,0}, floatx4{0,0,0,0}, floatx4{0,0,0,0} };
    if (p >= 1) {  // layer1[t=p-1]: [h0[t], h1[t-1]] @ enc1_cat^T
      if (kh == 0) {
        gemm_lds(a1, apb0, enc1r,       1024, lj0, l15, quad, 0, 256);
        gemm_lds(a1, apb1, enc1r + 512, 1024, lj0, l15, quad, 0, 256);
      } else {
        gemm_lds(a1, apb0, enc1r,       1024, lj0, l15, quad, 256, 512);
        gemm_lds(a1, apb1, enc1r + 512, 1024, lj0, l15, quad, 256, 512);
      }
    }
    if (p <= 511) {  // layer0[t=p]: [x_t, h0[t-1]] @ enc0_cat^T
      if (kh == 0) {
        gemm_x128s(a0, Xenc, p, enc0r, 640, row0, lj0, lane);
        gemm_lds(a0, apb0, enc0r + 128, 640, lj0, l15, quad, 0, 192);
      } else {
        gemm_lds(a0, apb0, enc0r + 128, 640, lj0, l15, quad, 192, 512);
      }
    }
    __syncthreads();                       // A dead from here; xb alias safe
    if (kh == 1) {
      for (int gg = 0; gg < 4; ++gg) xb[XR(w4, 0, gg)] = a1[gg];
      for (int gg = 0; gg < 4; ++gg) xb[XR(w4, 1, gg)] = a0[gg];
    }
    __syncthreads();
    if (kh == 0) {
      if (p >= 1) {
        for (int gg = 0; gg < 4; ++gg) a1[gg] += xb[XR(w4, 0, gg)];
        cell_store(a1, c1, h1buf[nxt], bsum + 2048, row0, j0, lane);
      }
      if (p <= 511) {
        for (int gg = 0; gg < 4; ++gg) a0[gg] += xb[XR(w4, 1, gg)];
        cell_store(a0, c0, h0buf[nxt], bsum, row0, j0, lane);
      }
    }
    gbar();
  }

  // ---------------- decoder: 2 phases per step -------------------------------
  int cur0 = 0, cur1 = 1;  // h0[511] in buf0, h1[511] in buf1
  for (int t = 0; t < 96; ++t) {
    {  // layer0[t]: h0 @ dec_W_hh0^T + inp*W_ih0 (rank-1 in epilogue)
      stage(h0buf[cur0], H0_CHUNK);
      __syncthreads();
      floatx4 acc[4] = { floatx4{0,0,0,0}, floatx4{0,0,0,0}, floatx4{0,0,0,0}, floatx4{0,0,0,0} };
      if (kh == 0) gemm_lds(acc, apb0, dec0r, 512, lj0, l15, quad, 0, 256);
      else         gemm_lds(acc, apb0, dec0r, 512, lj0, l15, quad, 256, 512);
      __syncthreads();
      if (kh == 1) {
        for (int gg = 0; gg < 4; ++gg) xb[XR(w4, 0, gg)] = acc[gg];
      }
      __syncthreads();
      if (kh == 0) {
        for (int gg = 0; gg < 4; ++gg) acc[gg] += xb[XR(w4, 0, gg)];
        cell_store_dec0(acc, c0, h0buf[cur0 ^ 1], bsum + 4096, dWih0col,
                        din0, y, tfm, dout, t, row0, j0, lane);
      }
    }
    gbar();
    cur0 ^= 1;
    {  // layer1[t]: [h0'[t], h1[t-1]] @ dec1_cat^T, + fc into d_out
      stage(h0buf[cur0], H0_CHUNK);
      stage(h1buf[cur1], H1_CHUNK);
      __syncthreads();
      floatx4 acc[4] = { floatx4{0,0,0,0}, floatx4{0,0,0,0}, floatx4{0,0,0,0}, floatx4{0,0,0,0} };
      if (kh == 0) {
        gemm_lds(acc, apb0, dec1r,       1024, lj0, l15, quad, 0, 256);
        gemm_lds(acc, apb1, dec1r + 512, 1024, lj0, l15, quad, 0, 256);
      } else {
        gemm_lds(acc, apb0, dec1r,       1024, lj0, l15, quad, 256, 512);
        gemm_lds(acc, apb1, dec1r + 512, 1024, lj0, l15, quad, 256, 512);
      }
      __syncthreads();
      if (kh == 1) {
        for (int gg = 0; gg < 4; ++gg) xb[XR(w4, 0, gg)] = acc[gg];
      }
      __syncthreads();
      if (kh == 0) {
        for (int gg = 0; gg < 4; ++gg) acc[gg] += xb[XR(w4, 0, gg)];
        cell_store_dec1(acc, c1, h1buf[cur1 ^ 1], bsum + 6144, fcW, fcb,
                        dout, t, row0, j0, lane);
      }
    }
    gbar();
    cur1 ^= 1;
  }
}

// ---- prep kernels ----------------------------------------------------------
__global__ void prep_misc(float* c0, float* c1, u16* h0b, u16* h1b,
    float* dout, u32* bar, float* bsum,
    const float* ebih0, const float* ebhh0, const float* ebih1, const float* ebhh1,
    const float* dbih0, const float* dbhh0, const float* dbih1, const float* dbhh1,
    const float* Xdec, float* din0)
{
  const int idx = blockIdx.x * 256 + threadIdx.x;   // grid covers exactly 262144
  c0[idx] = 0.f; c1[idx] = 0.f;
  h0b[idx] = 0; h0b[idx + HB] = 0; h0b[idx + 2 * HB] = 0; h0b[idx + 3 * HB] = 0;
  h1b[idx] = 0; h1b[idx + HB] = 0; h1b[idx + 2 * HB] = 0; h1b[idx + 3 * HB] = 0;
  if (idx < 49152) dout[idx] = 0.f;
  if (idx < 8192) {
    const int which = idx >> 11, j = idx & 2047;
    float v;
    if (which == 0)      v = ebih0[j] + ebhh0[j];
    else if (which == 1) v = ebih1[j] + ebhh1[j];
    else if (which == 2) v = dbih0[j] + dbhh0[j];
    else                 v = dbih1[j] + dbhh1[j];
    bsum[idx] = v;
  }
  if (idx < 512) {   // dec_in0[b] = sum(X_decode[b,:,:])
    float s = 0.f;
    const float* p = Xdec + (size_t)idx * 768;
    for (int i = 0; i < 768; ++i) s += p[i];
    din0[idx] = s;
  }
  if (idx < 512) bar[idx] = 0u;
}

// packed split-write: row = hj*128 + g*32 + lj, pitch 2*S, lo at +S
__device__ __forceinline__ void wsplit2(u16* dst, int S, int j_src, int k, float w) {
  const int j = j_src & 511, gg = j_src >> 9;
  const int hj = j >> 5, lj = j & 31;
  const size_t base = (size_t)((hj << 7) + (gg << 5) + lj) * 2 * S + k;
  u16 hh = f2bf(w);
  dst[base] = hh;
  dst[base + S] = f2bf(w - bf2f(hh));
}

__global__ void prep_weights(u16* enc0, const float* eWih0, const float* eWhh0,
    u16* enc1, const float* eWih1, const float* eWhh1,
    u16* dec0, const float* dWhh0,
    u16* dec1, const float* dWih1, const float* dWhh1)
{
  const int idx = blockIdx.x * 256 + threadIdx.x;   // grid covers 2097152
  if (idx < 2048 * 640) {
    const int j = idx / 640, k = idx - j * 640;
    wsplit2(enc0, 640, j, k,
            k < 128 ? eWih0[j * 128 + k] : eWhh0[j * 512 + (k - 128)]);
  }
  {
    const int j = idx >> 10, k = idx & 1023;
    wsplit2(enc1, 1024, j, k,
            k < 512 ? eWih1[(j << 9) + k] : eWhh1[(j << 9) + k - 512]);
    wsplit2(dec1, 1024, j, k,
            k < 512 ? dWih1[(j << 9) + k] : dWhh1[(j << 9) + k - 512]);
  }
  if (idx < 2048 * 512) {
    const int j = idx >> 9, k = idx & 511;
    wsplit2(dec0, 512, j, k, dWhh0[idx]);
  }
}

// ---- launch ----------------------------------------------------------------
extern "C" void kernel_launch(void* const* d_in, const int* in_sizes, int n_in,
                              void* d_out, int out_size, void* d_ws, size_t ws_size,
                              hipStream_t stream)
{
  const float* Xenc  = (const float*)d_in[0];
  const float* Xdec  = (const float*)d_in[1];
  const float* y     = (const float*)d_in[2];
  const int*   tfm   = (const int*)d_in[3];
  const float* eWih0 = (const float*)d_in[4];
  const float* eWhh0 = (const float*)d_in[5];
  const float* ebih0 = (const float*)d_in[6];
  const float* ebhh0 = (const float*)d_in[7];
  const float* eWih1 = (const float*)d_in[8];
  const float* eWhh1 = (const float*)d_in[9];
  const float* ebih1 = (const float*)d_in[10];
  const float* ebhh1 = (const float*)d_in[11];
  const float* dWih0 = (const float*)d_in[12];
  const float* dWhh0 = (const float*)d_in[13];
  const float* dbih0 = (const float*)d_in[14];
  const float* dbhh0 = (const float*)d_in[15];
  const float* dWih1 = (const float*)d_in[16];
  const float* dWhh1 = (const float*)d_in[17];
  const float* dbih1 = (const float*)d_in[18];
  const float* dbhh1 = (const float*)d_in[19];
  const float* fcW   = (const float*)d_in[20];
  const float* fcb   = (const float*)d_in[21];
  float* dout = (float*)d_out;

  char* base = (char*)d_ws;
  size_t off = 0;
  auto alloc = [&](size_t n) -> char* {
    char* p = base + off;
    off = (off + n + 255) & ~(size_t)255;
    return p;
  };
  u32* bar  = (u32*)alloc(512 * 4);
  u16* enc0 = (u16*)alloc((size_t)ENC0_REG * 16 * 2);   // 16 regions, 2B each
  u16* enc1 = (u16*)alloc((size_t)ENC1_REG * 16 * 2);
  u16* dec0 = (u16*)alloc((size_t)DEC0_REG * 16 * 2);
  u16* dec1 = (u16*)alloc((size_t)DEC1_REG * 16 * 2);
  u16* h0b  = (u16*)alloc((size_t)4 * HB * 2);   // 2 bufs x {hi,lo}
  u16* h1b  = (u16*)alloc((size_t)4 * HB * 2);
  float* c0 = (float*)alloc((size_t)HB * 4);
  float* c1 = (float*)alloc((size_t)HB * 4);
  float* bs = (float*)alloc((size_t)8192 * 4);
  float* di = (float*)alloc((size_t)512 * 4);

  static int lds_attr_set = 0;
  if (!lds_attr_set) {
    (void)hipFuncSetAttribute((const void*)seq2seq_persist,
        hipFuncAttributeMaxDynamicSharedMemorySize, 131072);
    lds_attr_set = 1;
  }

  prep_misc<<<1024, 256, 0, stream>>>(c0, c1, h0b, h1b, dout, bar, bs,
      ebih0, ebhh0, ebih1, ebhh1, dbih0, dbhh0, dbih1, dbhh1, Xdec, di);
  prep_weights<<<8192, 256, 0, stream>>>(enc0, eWih0, eWhh0, enc1, eWih1, eWhh1,
      dec0, dWhh0, dec1, dWih1, dWhh1);
  seq2seq_persist<<<NWG, 512, 131072, stream>>>(Xenc, y, tfm, dWih0, fcW, fcb,
      enc0, enc1, dec0, dec1, h0b, h1b, c0, c1, bs, di, dout, bar);
}

// Round 5
// 34373.239 us; speedup vs baseline: 1.1310x; 1.1310x over previous
//
#include <hip/hip_runtime.h>

// Seq2Seq LSTM (2-layer enc 512 steps + 2-layer dec 96 steps), B=512, H=512.
// R9 = R8 (packed per-hj_tile weights, LDS-staged A via global_load_lds,
//      512 thr / 8 waves, kh K-half split) with two changes:
//  (a) staged-h DMA aux reverted 0x13 -> 0x11 (drop NT; R8's only other
//      change vs R7 and the prime suspect for the 35.4->38.7 ms regression)
//  (b) per-b_tile barrier (16 WGs) instead of the 256-WG global barrier.
//      R5 tried this and FETCH exploded -- but that was with gate-major
//      weights whose 1 MB-strided blocks aliased 1/4 of L2's sets (way
//      size 256 KB): conflicted sets only survive lockstep sweeps. The
//      R8 packed layout spreads each XCD's ~1.7 MB slice over all sets
//      (~50% utilization), so residency now survives group drift.
//      16-WG barrier = one LLC counter, no two-level chain, no global
//      straggler coupling over 705 phases.
// Dependency closure per b_tile group (16 WGs, all hj): h (row-local,
// hj-partitioned), c (row+col local), dout (atomicAdd from exactly these
// 16 WGs), din0/y/tfm read-only. Verified R5 (passed with group barriers).

typedef unsigned int u32;
typedef unsigned short u16;

using bf16x8  = __attribute__((ext_vector_type(8))) __bf16;
using u16x8   = __attribute__((ext_vector_type(8))) u16;
using floatx4 = __attribute__((ext_vector_type(4))) float;

#define NWG 256
#define HB  262144   // 512*512 elements of one h/c plane

// packed region sizes (elements) per hj_tile: 128 rows x 2*K
#define ENC0_REG (128 * 2 * 640)
#define ENC1_REG (128 * 2 * 1024)
#define DEC0_REG (128 * 2 * 512)
#define DEC1_REG (128 * 2 * 1024)

// LDS map (dynamic, 131072 B):
//   [0..65536)      A-region H0: hi chunks ([k8][row]), lo at +32768 B
//   [65536..131072) A-region H1: same layout
//   xb reduce buffer (32 KB) aliases [0..32768) after GEMMs complete.
#define H0_CHUNK 0
#define H1_CHUNK 4096
#define LO_BYTES 32768

#define AS1C(p) ((const __attribute__((address_space(1))) void*)(p))
#define AS3(p)  ((__attribute__((address_space(3))) void*)(u32)(size_t)(p))

__device__ __forceinline__ u16 f2bf(float f) {
  u32 u = __builtin_bit_cast(u32, f);
  u += 0x7FFFu + ((u >> 16) & 1u);   // RNE
  return (u16)(u >> 16);
}
__device__ __forceinline__ float bf2f(u16 h) {
  return __builtin_bit_cast(float, (u32)h << 16);
}
__device__ __forceinline__ bf16x8 ld8(const u16* p) {           // cached (L1/L2)
  return __builtin_bit_cast(bf16x8, *reinterpret_cast<const u16x8*>(p));
}
__device__ __forceinline__ float sig_(float x) {
  x = fminf(fmaxf(x, -30.f), 30.f);
  return 1.f / (1.f + __expf(-x));
}
__device__ __forceinline__ float tanh_(float x) {
  x = fminf(fmaxf(x, -15.f), 15.f);
  float e = __expf(2.f * x);
  return (e - 1.f) / (e + 1.f);
}

#define MFMA(a, b, c) __builtin_amdgcn_mfma_f32_16x16x32_bf16((a), (b), (c), 0, 0, 0)

// ---- GEMM segment, A from LDS ([k8][row] chunks), W packed-region loads ----
// Wreg = region base (+K-offset for cat parts). Row (g*32+lj), pitch 2*S,
// lo plane at +S within the row.
__device__ __forceinline__ void gemm_lds(floatx4* acc, const char* apb,
    const u16* __restrict__ Wreg, int strideW,
    int lj0, int l15, int quad, int kbeg, int kend)
{
  const u16* wp = Wreg + (size_t)(lj0 + l15) * 2 * strideW + (quad << 3);
  const size_t gs = (size_t)strideW << 6;   // 32 rows * 2 * strideW
  #pragma unroll 2
  for (int k = kbeg; k < kend; k += 32) {
    const int kb8 = ((k >> 3) + quad) << 9;          // k8 * 512 bytes
    bf16x8 ah = *reinterpret_cast<const bf16x8*>(apb + kb8);
    bf16x8 al = *reinterpret_cast<const bf16x8*>(apb + kb8 + LO_BYTES);
    #pragma unroll
    for (int g = 0; g < 4; ++g) {
      bf16x8 wh = ld8(wp + k + g * gs);
      bf16x8 wl = ld8(wp + k + g * gs + strideW);
      acc[g] = MFMA(ah, wh, acc[g]);
      acc[g] = MFMA(ah, wl, acc[g]);
      acc[g] = MFMA(al, wh, acc[g]);
    }
  }
}

// ---- K=128 segment reading X_encode fp32 (B,T,128), split on the fly -------
__device__ __forceinline__ void gemm_x128s(floatx4* acc,
    const float* __restrict__ X, int t,
    const u16* __restrict__ Wreg, int strideW,
    int row0, int lj0, int lane)
{
  const int quad = lane >> 4, l15 = lane & 15;
  const float* xp = X + ((size_t)(row0 + l15) * 512 + t) * 128 + (quad << 3);
  const u16* wp = Wreg + (size_t)(lj0 + l15) * 2 * strideW + (quad << 3);
  const size_t gs = (size_t)strideW << 6;
  #pragma unroll
  for (int k = 0; k < 128; k += 32) {
    floatx4 xa = *reinterpret_cast<const floatx4*>(xp + k);
    floatx4 xb_ = *reinterpret_cast<const floatx4*>(xp + k + 4);
    u16x8 uh, ul;
    #pragma unroll
    for (int i = 0; i < 4; ++i) {
      u16 h0 = f2bf(xa[i]);  uh[i] = h0;     ul[i] = f2bf(xa[i] - bf2f(h0));
      u16 h1 = f2bf(xb_[i]); uh[4 + i] = h1; ul[4 + i] = f2bf(xb_[i] - bf2f(h1));
    }
    bf16x8 ah = __builtin_bit_cast(bf16x8, uh);
    bf16x8 al = __builtin_bit_cast(bf16x8, ul);
    #pragma unroll
    for (int g = 0; g < 4; ++g) {
      bf16x8 wh = ld8(wp + k + g * gs);
      bf16x8 wl = ld8(wp + k + g * gs + strideW);
      acc[g] = MFMA(ah, wh, acc[g]);
      acc[g] = MFMA(ah, wl, acc[g]);
      acc[g] = MFMA(al, wh, acc[g]);
    }
  }
}

__device__ __forceinline__ void store_h_split(u16* __restrict__ hout,
                                              size_t off, float h) {
  u16 hh = f2bf(h);
  u16 hl = f2bf(h - bf2f(hh));
  __hip_atomic_store(hout + off,      hh, __ATOMIC_RELAXED, __HIP_MEMORY_SCOPE_AGENT);
  __hip_atomic_store(hout + off + HB, hl, __ATOMIC_RELAXED, __HIP_MEMORY_SCOPE_AGENT);
}

// ---- LSTM cell epilogues (C/D layout: col=lane&15, row=(lane>>4)*4+reg) ----
__device__ __forceinline__ void cell_store(const floatx4* acc,
    float* __restrict__ c, u16* __restrict__ hout,
    const float* __restrict__ bs, int row0, int j0, int lane)
{
  const int quad = lane >> 4, l15 = lane & 15;
  const int col = j0 + l15;
  const float bi = bs[col], bff = bs[512 + col], bg = bs[1024 + col], bo = bs[1536 + col];
  const int r0 = row0 + (quad << 2);
  #pragma unroll
  for (int r = 0; r < 4; ++r) {
    const size_t off = ((size_t)(r0 + r) << 9) + col;
    float ii = sig_(acc[0][r] + bi);
    float ff = sig_(acc[1][r] + bff);
    float gg = tanh_(acc[2][r] + bg);
    float oo = sig_(acc[3][r] + bo);
    float cn = ff * c[off] + ii * gg;
    c[off] = cn;
    store_h_split(hout, off, oo * tanh_(cn));
  }
}

// decoder layer0: adds rank-1 input term inp[b]*W_ih0[j] (fp32, exact)
__device__ __forceinline__ void cell_store_dec0(const floatx4* acc,
    float* __restrict__ c, u16* __restrict__ hout,
    const float* __restrict__ bs, const float* __restrict__ w0col,
    const float* __restrict__ din0, const float* __restrict__ y,
    const int* __restrict__ tfm, float* __restrict__ dout,
    int t, int row0, int j0, int lane)
{
  const int quad = lane >> 4, l15 = lane & 15;
  const int col = j0 + l15;
  const float bi = bs[col], bff = bs[512 + col], bg = bs[1024 + col], bo = bs[1536 + col];
  const float wi = w0col[col], wf = w0col[512 + col], wg = w0col[1024 + col], wo = w0col[1536 + col];
  const int r0 = row0 + (quad << 2);
  #pragma unroll
  for (int r = 0; r < 4; ++r) {
    const int row = r0 + r;
    float inp;
    if (t == 0) inp = din0[row];
    else if (tfm[t - 1] != 0) inp = y[row * 96 + t];
    else inp = __hip_atomic_load(dout + row * 96 + (t - 1),
                                 __ATOMIC_RELAXED, __HIP_MEMORY_SCOPE_AGENT);
    const size_t off = ((size_t)row << 9) + col;
    float ii = sig_(acc[0][r] + bi + inp * wi);
    float ff = sig_(acc[1][r] + bff + inp * wf);
    float gg = tanh_(acc[2][r] + bg + inp * wg);
    float oo = sig_(acc[3][r] + bo + inp * wo);
    float cn = ff * c[off] + ii * gg;
    c[off] = cn;
    store_h_split(hout, off, oo * tanh_(cn));
  }
}

// decoder layer1: cell + fc partial dot (shuffle-reduce 16 cols, atomicAdd)
__device__ __forceinline__ void cell_store_dec1(const floatx4* acc,
    float* __restrict__ c, u16* __restrict__ hout,
    const float* __restrict__ bs, const float* __restrict__ fcW,
    const float* __restrict__ fcb, float* __restrict__ dout,
    int t, int row0, int j0, int lane)
{
  const int quad = lane >> 4, l15 = lane & 15;
  const int col = j0 + l15;
  const float bi = bs[col], bff = bs[512 + col], bg = bs[1024 + col], bo = bs[1536 + col];
  const float fw = fcW[col];
  const int r0 = row0 + (quad << 2);
  float s[4];
  #pragma unroll
  for (int r = 0; r < 4; ++r) {
    const size_t off = ((size_t)(r0 + r) << 9) + col;
    float ii = sig_(acc[0][r] + bi);
    float ff = sig_(acc[1][r] + bff);
    float gg = tanh_(acc[2][r] + bg);
    float oo = sig_(acc[3][r] + bo);
    float cn = ff * c[off] + ii * gg;
    c[off] = cn;
    float h = oo * tanh_(cn);
    store_h_split(hout, off, h);
    s[r] = h * fw;
  }
  #pragma unroll
  for (int m = 1; m < 16; m <<= 1) {
    #pragma unroll
    for (int r = 0; r < 4; ++r) s[r] += __shfl_xor(s[r], m, 64);
  }
  if (l15 == 0) {
    #pragma unroll
    for (int r = 0; r < 4; ++r) {
      float v = s[r];
      if (j0 == 0) v += fcb[0];            // exactly one wave per (b,t) adds bias
      atomicAdd(&dout[(size_t)(r0 + r) * 96 + t], v);
    }
  }
}

// ---- persistent kernel -----------------------------------------------------
__global__ __launch_bounds__(512) void seq2seq_persist(
    const float* __restrict__ Xenc, const float* __restrict__ y,
    const int* __restrict__ tfm, const float* __restrict__ dWih0col,
    const float* __restrict__ fcW, const float* __restrict__ fcb,
    const u16* __restrict__ enc0, const u16* __restrict__ enc1,
    const u16* __restrict__ dec0w, const u16* __restrict__ dec1,
    u16* __restrict__ h0bufs, u16* __restrict__ h1bufs,
    float* __restrict__ c0, float* __restrict__ c1,
    const float* __restrict__ bsum, const float* __restrict__ din0,
    float* __restrict__ dout, u32* __restrict__ bar)
{
  extern __shared__ char smem_c[];
  const int tid = threadIdx.x;
  const int g = blockIdx.x;
  const int wave = tid >> 6, lane = tid & 63;
  const int w4 = wave & 3, kh = wave >> 2;      // tile-quadrant, K-half
  const int quad = lane >> 4, l15 = lane & 15;
  // XCD-aware swizzle: WGs sharing a W-slab (same hj_tile) land on one XCD
  const int q = g >> 3;
  const int hj_tile = (g & 7) + ((q & 1) << 3);  // 0..15
  const int b_tile = q >> 1;                     // 0..15 (= barrier group)
  const int b0 = b_tile << 5, hj0 = hj_tile << 5;
  const int row0 = b0 + ((w4 & 1) << 4);         // 16 batch rows
  const int j0 = hj0 + ((w4 >> 1) << 4);         // 16 h-cols (global)
  const int lj0 = (w4 >> 1) << 4;                // local col within hj region
  u16* h0buf[2] = { h0bufs, h0bufs + 2 * HB };
  u16* h1buf[2] = { h1bufs, h1bufs + 2 * HB };
  unsigned ep = 0;

  // packed weight region bases for this hj_tile
  const u16* enc0r = enc0  + (size_t)hj_tile * ENC0_REG;
  const u16* enc1r = enc1  + (size_t)hj_tile * ENC1_REG;
  const u16* dec0r = dec0w + (size_t)hj_tile * DEC0_REG;
  const u16* dec1r = dec1  + (size_t)hj_tile * DEC1_REG;

  // A-fragment base pointers (row within WG = (w4&1)*16 + l15)
  const int lrow = ((w4 & 1) << 4) + l15;
  const char* apb0 = smem_c + lrow * 16;           // H0 region
  const char* apb1 = smem_c + 65536 + lrow * 16;   // H1 region
  floatx4* xb = (floatx4*)smem_c;                  // 32 KB alias (dead-A reuse)
  #define XR(w4_, L_, g_) (((((w4_) * 2 + (L_)) * 4 + (g_)) << 6) + lane)

  // stage one h buffer (hi plane + lo at +HB) into an A-region.
  // chunk c in [0,4096): half=c>>11 (hi/lo), k8=(c&2047)>>5, row=c&31.
  // aux 0x11 = SC0|SC1: L1/L2-bypass, LLC-coherent (R7 setting).
  auto stage = [&](const u16* hbuf, int region_chunk) {
    #pragma unroll
    for (int blk = 0; blk < 8; ++blk) {
      const int cw = (blk << 9) + (wave << 6);        // wave-uniform chunk base
      const int c  = cw + lane;
      const int half = c >> 11, cc = c & 2047;
      const int k8 = cc >> 5, row = cc & 31;
      const u16* src = hbuf + (size_t)half * HB
                     + ((size_t)(b0 + row) << 9) + (k8 << 3);
      __builtin_amdgcn_global_load_lds(
          AS1C(src), AS3(smem_c + (size_t)(region_chunk + cw) * 16),
          16, 0, 0x11 /* SC0|SC1 */);
    }
  };

  // per-b_tile barrier: 16 WGs, one monotonic relaxed LLC counter (own line).
  // vmcnt(0) drain before s_barrier orders stores < counter add.
  auto gbar = [&]() {
    __syncthreads();
    ++ep;
    if (tid == 0) {
      __hip_atomic_fetch_add(&bar[b_tile * 64], 1u,
                             __ATOMIC_RELAXED, __HIP_MEMORY_SCOPE_AGENT);
      while (__hip_atomic_load(&bar[b_tile * 64],
                 __ATOMIC_RELAXED, __HIP_MEMORY_SCOPE_AGENT) < ep * 16u)
        __builtin_amdgcn_s_sleep(1);
    }
    asm volatile("" ::: "memory");
    __syncthreads();
  };

  // ---------------- encoder: phase p does layer1[p-1] and layer0[p] ----------
  for (int p = 0; p <= 512; ++p) {
    const int cur = p & 1, nxt = cur ^ 1;
    stage(h0buf[cur], H0_CHUNK);
    stage(h1buf[cur], H1_CHUNK);
    __syncthreads();                       // drains staging vmcnt
    floatx4 a1[4] = { floatx4{0,0,0,0}, floatx4{0,0,0,0}, floatx4{0,0,0,0}, floatx4{0,0,0,0} };
    floatx4 a0[4] = { floatx4{0,0,0,0}, floatx4{0,0,0,0}, floatx4{0,0,0,0}, floatx4{0,0,0,0} };
    if (p >= 1) {  // layer1[t=p-1]: [h0[t], h1[t-1]] @ enc1_cat^T
      if (kh == 0) {
        gemm_lds(a1, apb0, enc1r,       1024, lj0, l15, quad, 0, 256);
        gemm_lds(a1, apb1, enc1r + 512, 1024, lj0, l15, quad, 0, 256);
      } else {
        gemm_lds(a1, apb0, enc1r,       1024, lj0, l15, quad, 256, 512);
        gemm_lds(a1, apb1, enc1r + 512, 1024, lj0, l15, quad, 256, 512);
      }
    }
    if (p <= 511) {  // layer0[t=p]: [x_t, h0[t-1]] @ enc0_cat^T
      if (kh == 0) {
        gemm_x128s(a0, Xenc, p, enc0r, 640, row0, lj0, lane);
        gemm_lds(a0, apb0, enc0r + 128, 640, lj0, l15, quad, 0, 192);
      } else {
        gemm_lds(a0, apb0, enc0r + 128, 640, lj0, l15, quad, 192, 512);
      }
    }
    __syncthreads();                       // A dead from here; xb alias safe
    if (kh == 1) {
      for (int gg = 0; gg < 4; ++gg) xb[XR(w4, 0, gg)] = a1[gg];
      for (int gg = 0; gg < 4; ++gg) xb[XR(w4, 1, gg)] = a0[gg];
    }
    __syncthreads();
    if (kh == 0) {
      if (p >= 1) {
        for (int gg = 0; gg < 4; ++gg) a1[gg] += xb[XR(w4, 0, gg)];
        cell_store(a1, c1, h1buf[nxt], bsum + 2048, row0, j0, lane);
      }
      if (p <= 511) {
        for (int gg = 0; gg < 4; ++gg) a0[gg] += xb[XR(w4, 1, gg)];
        cell_store(a0, c0, h0buf[nxt], bsum, row0, j0, lane);
      }
    }
    gbar();
  }

  // ---------------- decoder: 2 phases per step -------------------------------
  int cur0 = 0, cur1 = 1;  // h0[511] in buf0, h1[511] in buf1
  for (int t = 0; t < 96; ++t) {
    {  // layer0[t]: h0 @ dec_W_hh0^T + inp*W_ih0 (rank-1 in epilogue)
      stage(h0buf[cur0], H0_CHUNK);
      __syncthreads();
      floatx4 acc[4] = { floatx4{0,0,0,0}, floatx4{0,0,0,0}, floatx4{0,0,0,0}, floatx4{0,0,0,0} };
      if (kh == 0) gemm_lds(acc, apb0, dec0r, 512, lj0, l15, quad, 0, 256);
      else         gemm_lds(acc, apb0, dec0r, 512, lj0, l15, quad, 256, 512);
      __syncthreads();
      if (kh == 1) {
        for (int gg = 0; gg < 4; ++gg) xb[XR(w4, 0, gg)] = acc[gg];
      }
      __syncthreads();
      if (kh == 0) {
        for (int gg = 0; gg < 4; ++gg) acc[gg] += xb[XR(w4, 0, gg)];
        cell_store_dec0(acc, c0, h0buf[cur0 ^ 1], bsum + 4096, dWih0col,
                        din0, y, tfm, dout, t, row0, j0, lane);
      }
    }
    gbar();
    cur0 ^= 1;
    {  // layer1[t]: [h0'[t], h1[t-1]] @ dec1_cat^T, + fc into d_out
      stage(h0buf[cur0], H0_CHUNK);
      stage(h1buf[cur1], H1_CHUNK);
      __syncthreads();
      floatx4 acc[4] = { floatx4{0,0,0,0}, floatx4{0,0,0,0}, floatx4{0,0,0,0}, floatx4{0,0,0,0} };
      if (kh == 0) {
        gemm_lds(acc, apb0, dec1r,       1024, lj0, l15, quad, 0, 256);
        gemm_lds(acc, apb1, dec1r + 512, 1024, lj0, l15, quad, 0, 256);
      } else {
        gemm_lds(acc, apb0, dec1r,       1024, lj0, l15, quad, 256, 512);
        gemm_lds(acc, apb1, dec1r + 512, 1024, lj0, l15, quad, 256, 512);
      }
      __syncthreads();
      if (kh == 1) {
        for (int gg = 0; gg < 4; ++gg) xb[XR(w4, 0, gg)] = acc[gg];
      }
      __syncthreads();
      if (kh == 0) {
        for (int gg = 0; gg < 4; ++gg) acc[gg] += xb[XR(w4, 0, gg)];
        cell_store_dec1(acc, c1, h1buf[cur1 ^ 1], bsum + 6144, fcW, fcb,
                        dout, t, row0, j0, lane);
      }
    }
    gbar();
    cur1 ^= 1;
  }
}

// ---- prep kernels ----------------------------------------------------------
__global__ void prep_misc(float* c0, float* c1, u16* h0b, u16* h1b,
    float* dout, u32* bar, float* bsum,
    const float* ebih0, const float* ebhh0, const float* ebih1, const float* ebhh1,
    const float* dbih0, const float* dbhh0, const float* dbih1, const float* dbhh1,
    const float* Xdec, float* din0)
{
  const int idx = blockIdx.x * 256 + threadIdx.x;   // grid covers exactly 262144
  c0[idx] = 0.f; c1[idx] = 0.f;
  h0b[idx] = 0; h0b[idx + HB] = 0; h0b[idx + 2 * HB] = 0; h0b[idx + 3 * HB] = 0;
  h1b[idx] = 0; h1b[idx + HB] = 0; h1b[idx + 2 * HB] = 0; h1b[idx + 3 * HB] = 0;
  if (idx < 49152) dout[idx] = 0.f;
  if (idx < 8192) {
    const int which = idx >> 11, j = idx & 2047;
    float v;
    if (which == 0)      v = ebih0[j] + ebhh0[j];
    else if (which == 1) v = ebih1[j] + ebhh1[j];
    else if (which == 2) v = dbih0[j] + dbhh0[j];
    else                 v = dbih1[j] + dbhh1[j];
    bsum[idx] = v;
  }
  if (idx < 512) {   // dec_in0[b] = sum(X_decode[b,:,:])
    float s = 0.f;
    const float* p = Xdec + (size_t)idx * 768;
    for (int i = 0; i < 768; ++i) s += p[i];
    din0[idx] = s;
  }
  if (idx < 1024) bar[idx] = 0u;   // 16 group counters, 256B apart
}

// packed split-write: row = hj*128 + g*32 + lj, pitch 2*S, lo at +S
__device__ __forceinline__ void wsplit2(u16* dst, int S, int j_src, int k, float w) {
  const int j = j_src & 511, gg = j_src >> 9;
  const int hj = j >> 5, lj = j & 31;
  const size_t base = (size_t)((hj << 7) + (gg << 5) + lj) * 2 * S + k;
  u16 hh = f2bf(w);
  dst[base] = hh;
  dst[base + S] = f2bf(w - bf2f(hh));
}

__global__ void prep_weights(u16* enc0, const float* eWih0, const float* eWhh0,
    u16* enc1, const float* eWih1, const float* eWhh1,
    u16* dec0, const float* dWhh0,
    u16* dec1, const float* dWih1, const float* dWhh1)
{
  const int idx = blockIdx.x * 256 + threadIdx.x;   // grid covers 2097152
  if (idx < 2048 * 640) {
    const int j = idx / 640, k = idx - j * 640;
    wsplit2(enc0, 640, j, k,
            k < 128 ? eWih0[j * 128 + k] : eWhh0[j * 512 + (k - 128)]);
  }
  {
    const int j = idx >> 10, k = idx & 1023;
    wsplit2(enc1, 1024, j, k,
            k < 512 ? eWih1[(j << 9) + k] : eWhh1[(j << 9) + k - 512]);
    wsplit2(dec1, 1024, j, k,
            k < 512 ? dWih1[(j << 9) + k] : dWhh1[(j << 9) + k - 512]);
  }
  if (idx < 2048 * 512) {
    const int j = idx >> 9, k = idx & 511;
    wsplit2(dec0, 512, j, k, dWhh0[idx]);
  }
}

// ---- launch ----------------------------------------------------------------
extern "C" void kernel_launch(void* const* d_in, const int* in_sizes, int n_in,
                              void* d_out, int out_size, void* d_ws, size_t ws_size,
                              hipStream_t stream)
{
  const float* Xenc  = (const float*)d_in[0];
  const float* Xdec  = (const float*)d_in[1];
  const float* y     = (const float*)d_in[2];
  const int*   tfm   = (const int*)d_in[3];
  const float* eWih0 = (const float*)d_in[4];
  const float* eWhh0 = (const float*)d_in[5];
  const float* ebih0 = (const float*)d_in[6];
  const float* ebhh0 = (const float*)d_in[7];
  const float* eWih1 = (const float*)d_in[8];
  const float* eWhh1 = (const float*)d_in[9];
  const float* ebih1 = (const float*)d_in[10];
  const float* ebhh1 = (const float*)d_in[11];
  const float* dWih0 = (const float*)d_in[12];
  const float* dWhh0 = (const float*)d_in[13];
  const float* dbih0 = (const float*)d_in[14];
  const float* dbhh0 = (const float*)d_in[15];
  const float* dWih1 = (const float*)d_in[16];
  const float* dWhh1 = (const float*)d_in[17];
  const float* dbih1 = (const float*)d_in[18];
  const float* dbhh1 = (const float*)d_in[19];
  const float* fcW   = (const float*)d_in[20];
  const float* fcb   = (const float*)d_in[21];
  float* dout = (float*)d_out;

  char* base = (char*)d_ws;
  size_t off = 0;
  auto alloc = [&](size_t n) -> char* {
    char* p = base + off;
    off = (off + n + 255) & ~(size_t)255;
    return p;
  };
  u32* bar  = (u32*)alloc(1024 * 4);
  u16* enc0 = (u16*)alloc((size_t)ENC0_REG * 16 * 2);   // 16 regions, 2B each
  u16* enc1 = (u16*)alloc((size_t)ENC1_REG * 16 * 2);
  u16* dec0 = (u16*)alloc((size_t)DEC0_REG * 16 * 2);
  u16* dec1 = (u16*)alloc((size_t)DEC1_REG * 16 * 2);
  u16* h0b  = (u16*)alloc((size_t)4 * HB * 2);   // 2 bufs x {hi,lo}
  u16* h1b  = (u16*)alloc((size_t)4 * HB * 2);
  float* c0 = (float*)alloc((size_t)HB * 4);
  float* c1 = (float*)alloc((size_t)HB * 4);
  float* bs = (float*)alloc((size_t)8192 * 4);
  float* di = (float*)alloc((size_t)512 * 4);

  static int lds_attr_set = 0;
  if (!lds_attr_set) {
    (void)hipFuncSetAttribute((const void*)seq2seq_persist,
        hipFuncAttributeMaxDynamicSharedMemorySize, 131072);
    lds_attr_set = 1;
  }

  prep_misc<<<1024, 256, 0, stream>>>(c0, c1, h0b, h1b, dout, bar, bs,
      ebih0, ebhh0, ebih1, ebhh1, dbih0, dbhh0, dbih1, dbhh1, Xdec, di);
  prep_weights<<<8192, 256, 0, stream>>>(enc0, eWih0, eWhh0, enc1, eWih1, eWhh1,
      dec0, dWhh0, dec1, dWih1, dWhh1);
  seq2seq_persist<<<NWG, 512, 131072, stream>>>(Xenc, y, tfm, dWih0, fcW, fcb,
      enc0, enc1, dec0, dec1, h0b, h1b, c0, c1, bs, di, dout, bar);
}